// Round 2
// baseline (561.828 us; speedup 1.0000x reference)
//
#include <hip/hip_runtime.h>

typedef unsigned short u16;
typedef u16   u16x4 __attribute__((ext_vector_type(4)));
typedef u16   u16x8 __attribute__((ext_vector_type(8)));
typedef short s16x8 __attribute__((ext_vector_type(8)));
typedef float f32x4 __attribute__((ext_vector_type(4)));

#define NSEQ 256
#define NRES 384
#define NF   64
#define NP   32
#define NO   128

__device__ __forceinline__ u16 f2b(float f) {
    union { float f; unsigned u; } c; c.f = f;
    unsigned r = c.u + 0x7fffu + ((c.u >> 16) & 1u);   // RNE
    return (u16)(r >> 16);
}

// ---------------------------------------------------------------------------
// Kernel 0: convert Wo (f32, 128x1024) -> bf16 WoB. Grid 128 x 256.
// ---------------------------------------------------------------------------
__global__ __launch_bounds__(256) void k_prep(const float* __restrict__ Wo,
                                              u16* __restrict__ WoB)
{
    int idx = blockIdx.x * 256 + threadIdx.x;          // [0, 32768)
    f32x4 v = *(const f32x4*)(Wo + idx * 4);
    u16x4 o;
    #pragma unroll
    for (int e = 0; e < 4; ++e) o[e] = f2b(v[e]);
    *(u16x4*)(WoB + idx * 4) = o;
}

// ---------------------------------------------------------------------------
// Kernel 1: LayerNorm + dual projection + mask; writes leftT/rightT (bf16) in
// [ic = i*32+p][s] layout (K(s)-contiguous rows for MFMA fragment loads).
// Block: 256 thr = one residue i x 64 s-values. Grid (384, 4).
// ---------------------------------------------------------------------------
__global__ __launch_bounds__(256) void k_lnproj(
    const float* __restrict__ M, const float* __restrict__ mask,
    const float* __restrict__ gamma, const float* __restrict__ beta,
    const float* __restrict__ Wa, const float* __restrict__ ba,
    const float* __restrict__ Wb, const float* __restrict__ bb,
    u16* __restrict__ leftT, u16* __restrict__ rightT)
{
    __shared__ float Mt[64][68];        // [s][f], padded rows (272 B, 16B-aligned)
    __shared__ float Ws[2][32][68];     // [a/b][p][f]
    __shared__ float gs[64], bs[64], bias[64], mk[64];
    const int t  = threadIdx.x;
    const int i  = blockIdx.x;
    const int s0 = blockIdx.y * 64;
    const int s  = t >> 2, f0 = (t & 3) * 16;

    {   // stage M tile: each thread 16 contiguous f (64 B = 4x float4)
        const float* g = M + ((long)(s0 + s) * NRES + i) * NF + f0;
        #pragma unroll
        for (int q = 0; q < 4; ++q) {
            f32x4 v = *(const f32x4*)(g + q * 4);
            #pragma unroll
            for (int e = 0; e < 4; ++e) Mt[s][f0 + q * 4 + e] = v[e];
        }
    }
    {   // stage Wa/Wb (2048 f32 each = 256 thr x 8)
        f32x4 va0 = *(const f32x4*)(Wa + t * 8);
        f32x4 va1 = *(const f32x4*)(Wa + t * 8 + 4);
        f32x4 vb0 = *(const f32x4*)(Wb + t * 8);
        f32x4 vb1 = *(const f32x4*)(Wb + t * 8 + 4);
        int p = t >> 3, f = (t & 7) * 8;
        #pragma unroll
        for (int e = 0; e < 4; ++e) {
            Ws[0][p][f + e]     = va0[e];
            Ws[0][p][f + 4 + e] = va1[e];
            Ws[1][p][f + e]     = vb0[e];
            Ws[1][p][f + 4 + e] = vb1[e];
        }
    }
    if (t < 64) { gs[t] = gamma[t]; bs[t] = beta[t];
                  mk[t] = mask[(long)(s0 + t) * NRES + i]; }
    if (t < 32) { bias[t] = ba[t]; bias[32 + t] = bb[t]; }
    __syncthreads();

    // LN stats: 4 threads per s, shfl_xor within aligned group-of-4
    float sum = 0.f, sq = 0.f;
    #pragma unroll
    for (int e = 0; e < 16; ++e) { float v = Mt[s][f0 + e]; sum += v; sq += v * v; }
    sum += __shfl_xor(sum, 1); sq += __shfl_xor(sq, 1);
    sum += __shfl_xor(sum, 2); sq += __shfl_xor(sq, 2);
    float mu  = sum * (1.f / 64.f);
    float var = sq * (1.f / 64.f) - mu * mu;
    float rs  = rsqrtf(var + 1e-5f);
    #pragma unroll
    for (int e = 0; e < 16; ++e) {
        int f = f0 + e;
        Mt[s][f] = (Mt[s][f] - mu) * rs * gs[f] + bs[f];   // in-place Mn (own cells)
    }
    __syncthreads();

    // projections: thread -> (lr, p, 16 s-values); f32x4 LDS dot
    const int rowid = t >> 2, sg = t & 3;
    const int lr = rowid >> 5, p = rowid & 31;
    const float* Wp = &Ws[lr][p][0];
    float accv[16];
    #pragma unroll
    for (int e = 0; e < 16; ++e) accv[e] = 0.f;
    #pragma unroll 4
    for (int f4 = 0; f4 < 16; ++f4) {
        f32x4 w4 = *(const f32x4*)(Wp + f4 * 4);
        #pragma unroll
        for (int e = 0; e < 16; ++e) {
            f32x4 m4 = *(const f32x4*)(&Mt[sg * 16 + e][f4 * 4]);
            accv[e] += m4[0]*w4[0] + m4[1]*w4[1] + m4[2]*w4[2] + m4[3]*w4[3];
        }
    }
    const float b_ = bias[lr * 32 + p];
    u16x8 o0, o1;
    #pragma unroll
    for (int e = 0; e < 8; ++e) o0[e] = f2b((accv[e]     + b_) * mk[sg * 16 + e]);
    #pragma unroll
    for (int e = 0; e < 8; ++e) o1[e] = f2b((accv[8 + e] + b_) * mk[sg * 16 + 8 + e]);
    u16* dst = (lr ? rightT : leftT) + ((long)i * NP + p) * NSEQ + s0 + sg * 16;
    *(u16x8*)dst       = o0;
    *(u16x8*)(dst + 8) = o1;
}

// ---------------------------------------------------------------------------
// Kernel 2: norm[i][j] = sum_s mask[s][i]*mask[s][j].  Grid (24,24) x 256.
// ---------------------------------------------------------------------------
__global__ __launch_bounds__(256) void k_norm(const float* __restrict__ mask,
                                              float* __restrict__ normMat)
{
    __shared__ float mi[256][17], mj[256][17];
    const int t  = threadIdx.x;
    const int iB = blockIdx.x * 16, jB = blockIdx.y * 16;
    #pragma unroll
    for (int it = 0; it < 16; ++it) {
        int ss = it * 16 + (t >> 4);
        int c  = t & 15;
        mi[ss][c] = mask[(long)ss * NRES + iB + c];
        mj[ss][c] = mask[(long)ss * NRES + jB + c];
    }
    __syncthreads();
    const int ti = t >> 4, tj = t & 15;
    float acc = 0.f;
    for (int ss = 0; ss < 256; ++ss) acc += mi[ss][ti] * mj[ss][tj];
    normMat[(long)(iB + ti) * NRES + jB + tj] = acc;
}

// ---------------------------------------------------------------------------
// Kernel 3: fused outer-product GEMM (128x128 tile, K=256 over s) +
// Wo projection (M=16 pairs, N=128, K=1024) + scale/bias/residual epilogue.
// Grid (96, 96) x 256 (4 waves; wave -> 64x64 quadrant).
// ---------------------------------------------------------------------------
__global__ __launch_bounds__(256) void k_main(
    const u16* __restrict__ leftT, const u16* __restrict__ rightT,
    const float* __restrict__ normMat,
    const u16* __restrict__ WoB, const float* __restrict__ bo,
    const float* __restrict__ Zraw, float* __restrict__ out)
{
    __shared__ __align__(16) char smem[32768];
    u16 (*As)[40]  = (u16 (*)[40])smem;            // [128 ic][32 s + pad8]
    u16 (*Bs)[40]  = (u16 (*)[40])(smem + 10240);  // [128 jd][32 s + pad8]
    u16 (*Os)[128] = (u16 (*)[128])smem;           // epilogue overlay: [128 ic][128 jd]

    const int t    = threadIdx.x;
    const int wave = t >> 6, lane = t & 63;
    const int quad = lane >> 4, l16 = lane & 15;
    const int wr = wave >> 1, wc = wave & 1;
    const long icBase = (long)blockIdx.x * 128;
    const long jdBase = (long)blockIdx.y * 128;

    f32x4 acc[4][4] = {};

    for (int k0 = 0; k0 < NSEQ; k0 += 32) {
        __syncthreads();
        #pragma unroll
        for (int h = 0; h < 2; ++h) {              // 512 x 16B chunks, 2 per thread
            int id = t + h * 256;
            int row = id >> 2, c8 = (id & 3) * 8;
            *(u16x8*)&As[row][c8] = *(const u16x8*)(leftT  + (icBase + row) * NSEQ + k0 + c8);
            *(u16x8*)&Bs[row][c8] = *(const u16x8*)(rightT + (jdBase + row) * NSEQ + k0 + c8);
        }
        __syncthreads();
        u16x8 af[4], bfr[4];
        #pragma unroll
        for (int mt = 0; mt < 4; ++mt)
            af[mt]  = *(const u16x8*)&As[wr * 64 + mt * 16 + l16][quad * 8];
        #pragma unroll
        for (int nt = 0; nt < 4; ++nt)
            bfr[nt] = *(const u16x8*)&Bs[wc * 64 + nt * 16 + l16][quad * 8];
        #pragma unroll
        for (int mt = 0; mt < 4; ++mt)
            #pragma unroll
            for (int nt = 0; nt < 4; ++nt)
                acc[mt][nt] = __builtin_amdgcn_mfma_f32_16x16x32_bf16(
                    (s16x8)af[mt], (s16x8)bfr[nt], acc[mt][nt], 0, 0, 0);
    }

    // O tile -> LDS bf16 (C/D layout: row = quad*4+reg, col = lane&15)
    __syncthreads();
    #pragma unroll
    for (int mt = 0; mt < 4; ++mt)
        #pragma unroll
        for (int nt = 0; nt < 4; ++nt)
            #pragma unroll
            for (int rg = 0; rg < 4; ++rg)
                Os[wr * 64 + mt * 16 + quad * 4 + rg][wc * 64 + nt * 16 + l16] = f2b(acc[mt][nt][rg]);
    __syncthreads();

    // Stage 2: Z2[pair][o] = sum_k O_pair[k] * Wo[o][k]
    // A-frag: m=pair=lane&15 (ii=m>>2, jj=m&3), k=kk*32+quad*8+j -> Os[ii*32+kk][jj*32+quad*8 ..]
    f32x4 acc2[2] = {};
    const int ob   = wave * 32;                    // wave's o-range (2 n-tiles)
    const int arow = (l16 >> 2) * 32;
    const int acol = (l16 & 3) * 32 + quad * 8;
    #pragma unroll 4
    for (int kk = 0; kk < 32; ++kk) {
        u16x8 a2 = *(const u16x8*)&Os[arow + kk][acol];
        #pragma unroll
        for (int nt = 0; nt < 2; ++nt) {
            int o = ob + nt * 16 + l16;
            u16x8 b2 = *(const u16x8*)(WoB + (long)o * 1024 + kk * 32 + quad * 8);
            acc2[nt] = __builtin_amdgcn_mfma_f32_16x16x32_bf16(
                (s16x8)a2, (s16x8)b2, acc2[nt], 0, 0, 0);
        }
    }

    // epilogue: (z + bo)/(0.001+norm) + Zraw  (f32 out)
    const int i0 = blockIdx.x * 4, j0 = blockIdx.y * 4;
    #pragma unroll
    for (int nt = 0; nt < 2; ++nt) {
        int o = ob + nt * 16 + l16;
        float bov = bo[o];
        #pragma unroll
        for (int rg = 0; rg < 4; ++rg) {
            int pair = quad * 4 + rg;              // D row = pair
            int i = i0 + (pair >> 2), j = j0 + (pair & 3);
            float nrm = normMat[(long)i * NRES + j];
            long off = ((long)i * NRES + j) * NO + o;
            out[off] = (acc2[nt][rg] + bov) / (0.001f + nrm) + Zraw[off];
        }
    }
}

extern "C" void kernel_launch(void* const* d_in, const int* in_sizes, int n_in,
                              void* d_out, int out_size, void* d_ws, size_t ws_size,
                              hipStream_t stream)
{
    const float* M     = (const float*)d_in[0];
    const float* mask  = (const float*)d_in[1];
    const float* Zraw  = (const float*)d_in[2];
    const float* gamma = (const float*)d_in[3];
    const float* beta  = (const float*)d_in[4];
    const float* Wa    = (const float*)d_in[5];
    const float* ba    = (const float*)d_in[6];
    const float* Wb    = (const float*)d_in[7];
    const float* bb    = (const float*)d_in[8];
    const float* Wo    = (const float*)d_in[9];
    const float* bo    = (const float*)d_in[10];
    float* out = (float*)d_out;

    char* ws = (char*)d_ws;
    u16*   leftT   = (u16*)ws;                      // 12288 x 256 bf16 = 6,291,456 B
    u16*   rightT  = (u16*)(ws + 6291456);          // 6,291,456 B
    float* normMat = (float*)(ws + 12582912);       // 384x384 f32 = 589,824 B
    u16*   WoB     = (u16*)(ws + 13172736);         // 128x1024 bf16 = 262,144 B

    k_prep<<<dim3(128), dim3(256), 0, stream>>>(Wo, WoB);
    k_lnproj<<<dim3(NRES, 4), dim3(256), 0, stream>>>(M, mask, gamma, beta,
                                                      Wa, ba, Wb, bb, leftT, rightT);
    k_norm<<<dim3(24, 24), dim3(256), 0, stream>>>(mask, normMat);
    k_main<<<dim3(96, 96), dim3(256), 0, stream>>>(leftT, rightT, normMat,
                                                   WoB, bo, Zraw, out);
}

// Round 3
// 545.842 us; speedup vs baseline: 1.0293x; 1.0293x over previous
//
#include <hip/hip_runtime.h>

typedef unsigned short u16;
typedef u16   u16x4 __attribute__((ext_vector_type(4)));
typedef u16   u16x8 __attribute__((ext_vector_type(8)));
typedef short s16x8 __attribute__((ext_vector_type(8)));
typedef float f32x4 __attribute__((ext_vector_type(4)));

#define NSEQ 256
#define NRES 384
#define NF   64
#define NP   32
#define NO   128

__device__ __forceinline__ u16 f2b(float f) {
    union { float f; unsigned u; } c; c.f = f;
    unsigned r = c.u + 0x7fffu + ((c.u >> 16) & 1u);   // RNE
    return (u16)(r >> 16);
}

// async global->LDS, 16B per lane; LDS dest = wave-uniform base + lane*16
__device__ __forceinline__ void gload_lds16(const u16* g, u16* l) {
    __builtin_amdgcn_global_load_lds(
        (const __attribute__((address_space(1))) unsigned int*)(g),
        (__attribute__((address_space(3))) unsigned int*)(l),
        16, 0, 0);
}

// ---------------------------------------------------------------------------
// Kernel 0: convert Wo (f32, 128x1024) -> bf16 WoB. Grid 128 x 256.
// ---------------------------------------------------------------------------
__global__ __launch_bounds__(256) void k_prep(const float* __restrict__ Wo,
                                              u16* __restrict__ WoB)
{
    int idx = blockIdx.x * 256 + threadIdx.x;          // [0, 32768)
    f32x4 v = *(const f32x4*)(Wo + idx * 4);
    u16x4 o;
    #pragma unroll
    for (int e = 0; e < 4; ++e) o[e] = f2b(v[e]);
    *(u16x4*)(WoB + idx * 4) = o;
}

// ---------------------------------------------------------------------------
// Kernel 1: LayerNorm + dual projection + mask -> leftT/rightT (bf16) in
// [ic = i*32+p][s] layout. Block 256 = residue i x 64 s. Grid (384, 4).
// Projection phase: W row in VGPRs (global, L2-hot); Mt reads are
// wave-uniform broadcasts (sg = wave id) -> zero bank conflicts.
// ---------------------------------------------------------------------------
__global__ __launch_bounds__(256) void k_lnproj(
    const float* __restrict__ M, const float* __restrict__ mask,
    const float* __restrict__ gamma, const float* __restrict__ beta,
    const float* __restrict__ Wa, const float* __restrict__ ba,
    const float* __restrict__ Wb, const float* __restrict__ bb,
    u16* __restrict__ leftT, u16* __restrict__ rightT)
{
    __shared__ float Mt[64][68];        // [s][f], 272 B rows (16B-aligned)
    __shared__ float gs[64], bs[64], bias[64], mk[64];
    const int t  = threadIdx.x;
    const int i  = blockIdx.x;
    const int s0 = blockIdx.y * 64;
    const int s  = t >> 2, f0 = (t & 3) * 16;

    {   // stage M tile: thread -> 16 contiguous f (64 B)
        const float* g = M + ((long)(s0 + s) * NRES + i) * NF + f0;
        #pragma unroll
        for (int q = 0; q < 4; ++q) {
            f32x4 v = *(const f32x4*)(g + q * 4);
            #pragma unroll
            for (int e = 0; e < 4; ++e) Mt[s][f0 + q * 4 + e] = v[e];
        }
    }
    if (t < 64) { gs[t] = gamma[t]; bs[t] = beta[t];
                  mk[t] = mask[(long)(s0 + t) * NRES + i]; }
    if (t < 32) { bias[t] = ba[t]; bias[32 + t] = bb[t]; }
    __syncthreads();

    // LN stats: 4 threads per s, shfl_xor within aligned group-of-4
    float sum = 0.f, sq = 0.f;
    #pragma unroll
    for (int e = 0; e < 16; ++e) { float v = Mt[s][f0 + e]; sum += v; sq += v * v; }
    sum += __shfl_xor(sum, 1); sq += __shfl_xor(sq, 1);
    sum += __shfl_xor(sum, 2); sq += __shfl_xor(sq, 2);
    float mu  = sum * (1.f / 64.f);
    float var = sq * (1.f / 64.f) - mu * mu;
    float rs  = rsqrtf(var + 1e-5f);
    #pragma unroll
    for (int e = 0; e < 16; ++e) {
        int f = f0 + e;
        Mt[s][f] = (Mt[s][f] - mu) * rs * gs[f] + bs[f];
    }
    __syncthreads();

    // projection mapping: sg = wave (uniform), rowid = lane -> (lr, p)
    const int sg = t >> 6, rowid = t & 63;
    const int lr = rowid >> 5, p = rowid & 31;
    const float* Wg = (lr ? Wb : Wa) + p * 64;
    f32x4 wreg[16];
    #pragma unroll
    for (int q = 0; q < 16; ++q) wreg[q] = *(const f32x4*)(Wg + q * 4);

    float accv[16];
    #pragma unroll
    for (int e = 0; e < 16; ++e) accv[e] = 0.f;
    #pragma unroll 4
    for (int f4 = 0; f4 < 16; ++f4) {
        f32x4 w4 = wreg[f4];
        #pragma unroll
        for (int e = 0; e < 16; ++e) {
            f32x4 m4 = *(const f32x4*)(&Mt[sg * 16 + e][f4 * 4]);  // broadcast
            accv[e] += m4[0]*w4[0] + m4[1]*w4[1] + m4[2]*w4[2] + m4[3]*w4[3];
        }
    }
    const float b_ = bias[rowid];
    u16x8 o0, o1;
    #pragma unroll
    for (int e = 0; e < 8; ++e) o0[e] = f2b((accv[e]     + b_) * mk[sg * 16 + e]);
    #pragma unroll
    for (int e = 0; e < 8; ++e) o1[e] = f2b((accv[8 + e] + b_) * mk[sg * 16 + 8 + e]);
    u16* dst = (lr ? rightT : leftT) + ((long)i * NP + p) * NSEQ + s0 + sg * 16;
    *(u16x8*)dst       = o0;
    *(u16x8*)(dst + 8) = o1;
}

// ---------------------------------------------------------------------------
// Kernel 2: norm[i][j] = sum_s mask[s][i]*mask[s][j].  Grid (24,24) x 256.
// ---------------------------------------------------------------------------
__global__ __launch_bounds__(256) void k_norm(const float* __restrict__ mask,
                                              float* __restrict__ normMat)
{
    __shared__ float mi[256][17], mj[256][17];
    const int t  = threadIdx.x;
    const int iB = blockIdx.x * 16, jB = blockIdx.y * 16;
    #pragma unroll
    for (int it = 0; it < 16; ++it) {
        int ss = it * 16 + (t >> 4);
        int c  = t & 15;
        mi[ss][c] = mask[(long)ss * NRES + iB + c];
        mj[ss][c] = mask[(long)ss * NRES + jB + c];
    }
    __syncthreads();
    const int ti = t >> 4, tj = t & 15;
    float acc = 0.f;
    for (int ss = 0; ss < 256; ++ss) acc += mi[ss][ti] * mj[ss][tj];
    normMat[(long)(iB + ti) * NRES + jB + tj] = acc;
}

// ---------------------------------------------------------------------------
// Kernel 3: fused outer-product GEMM (128x128 tile, K=256, async LDS staging)
// + Wo projection (16 pairs x 128 outs x K=1024) + epilogue.
// Grid (96, 96) x 256 (4 waves).
// ---------------------------------------------------------------------------
__global__ __launch_bounds__(256) void k_main(
    const u16* __restrict__ leftT, const u16* __restrict__ rightT,
    const float* __restrict__ normMat,
    const u16* __restrict__ WoB, const float* __restrict__ bo,
    const float* __restrict__ Zraw, float* __restrict__ out)
{
    // As: [128][32] u16 unpadded (8 KB) at smem[0]
    // Bs: [128][32] u16 unpadded (8 KB) at smem[4096]
    // Os overlay: [128][136] u16 (34 KB) at smem[0]
    __shared__ __align__(16) u16 smem[128 * 136];

    const int t    = threadIdx.x;
    const int wave = t >> 6, lane = t & 63;
    const int quad = lane >> 4, l16 = lane & 15;
    const int wr = wave >> 1, wc = wave & 1;
    const long icBase = (long)blockIdx.x * 128;
    const long jdBase = (long)blockIdx.y * 128;

    f32x4 acc[4][4] = {};

    const int srow = (lane >> 2);            // staging: lane's row within seg
    const int sc8  = (lane & 3) * 8;         // staging: lane's 8-elem col chunk

    for (int k0 = 0; k0 < NSEQ; k0 += 32) {
        // async staging: each wave 2 segs of A + 2 segs of B (1 KB each)
        #pragma unroll
        for (int h = 0; h < 2; ++h) {
            int seg = wave * 2 + h;          // 0..7 -> rows [seg*16, seg*16+16)
            gload_lds16(leftT  + (icBase + seg * 16 + srow) * NSEQ + k0 + sc8,
                        &smem[seg * 512]);
            gload_lds16(rightT + (jdBase + seg * 16 + srow) * NSEQ + k0 + sc8,
                        &smem[4096 + seg * 512]);
        }
        __syncthreads();                     // drains vmcnt -> LDS visible

        u16x8 af[4], bfr[4];
        #pragma unroll
        for (int mt = 0; mt < 4; ++mt)
            af[mt]  = *(const u16x8*)&smem[(wr * 64 + mt * 16 + l16) * 32 + quad * 8];
        #pragma unroll
        for (int nt = 0; nt < 4; ++nt)
            bfr[nt] = *(const u16x8*)&smem[4096 + (wc * 64 + nt * 16 + l16) * 32 + quad * 8];
        #pragma unroll
        for (int mt = 0; mt < 4; ++mt)
            #pragma unroll
            for (int nt = 0; nt < 4; ++nt)
                acc[mt][nt] = __builtin_amdgcn_mfma_f32_16x16x32_bf16(
                    (s16x8)af[mt], (s16x8)bfr[nt], acc[mt][nt], 0, 0, 0);
        __syncthreads();                     // protect LDS before next staging
    }

    // O tile -> LDS bf16 overlay (C/D layout: row = quad*4+reg, col = l16)
    #pragma unroll
    for (int mt = 0; mt < 4; ++mt)
        #pragma unroll
        for (int nt = 0; nt < 4; ++nt)
            #pragma unroll
            for (int rg = 0; rg < 4; ++rg)
                smem[(wr * 64 + mt * 16 + quad * 4 + rg) * 136
                     + wc * 64 + nt * 16 + l16] = f2b(acc[mt][nt][rg]);
    __syncthreads();

    // Stage 2: Z2[pair][o] = sum_k O_pair[k] * Wo[o][k]
    // A-frag: m=pair=l16 (ii=m>>2, jj=m&3), k=kk*32+quad*8+j
    f32x4 acc2[2] = {};
    const int ob = wave * 32;
    const u16* Osp = &smem[((l16 >> 2) * 32) * 136 + (l16 & 3) * 32 + quad * 8];
    const u16* wp0 = WoB + (long)(ob + l16) * 1024 + quad * 8;
    const u16* wp1 = wp0 + 16 * 1024;
    #pragma unroll 8
    for (int kk = 0; kk < 32; ++kk) {
        u16x8 a2 = *(const u16x8*)(Osp + kk * 136);
        u16x8 b0 = *(const u16x8*)(wp0 + kk * 32);
        u16x8 b1 = *(const u16x8*)(wp1 + kk * 32);
        acc2[0] = __builtin_amdgcn_mfma_f32_16x16x32_bf16((s16x8)a2, (s16x8)b0, acc2[0], 0, 0, 0);
        acc2[1] = __builtin_amdgcn_mfma_f32_16x16x32_bf16((s16x8)a2, (s16x8)b1, acc2[1], 0, 0, 0);
    }

    // epilogue: (z + bo)/(0.001+norm) + Zraw  (f32 out)
    const int i0 = blockIdx.x * 4, j0 = blockIdx.y * 4;
    #pragma unroll
    for (int nt = 0; nt < 2; ++nt) {
        int o = ob + nt * 16 + l16;
        float bov = bo[o];
        #pragma unroll
        for (int rg = 0; rg < 4; ++rg) {
            int pair = quad * 4 + rg;              // D row = pair
            int i = i0 + (pair >> 2), j = j0 + (pair & 3);
            float nrm = normMat[(long)i * NRES + j];
            long off = ((long)i * NRES + j) * NO + o;
            out[off] = (acc2[nt][rg] + bov) / (0.001f + nrm) + Zraw[off];
        }
    }
}

extern "C" void kernel_launch(void* const* d_in, const int* in_sizes, int n_in,
                              void* d_out, int out_size, void* d_ws, size_t ws_size,
                              hipStream_t stream)
{
    const float* M     = (const float*)d_in[0];
    const float* mask  = (const float*)d_in[1];
    const float* Zraw  = (const float*)d_in[2];
    const float* gamma = (const float*)d_in[3];
    const float* beta  = (const float*)d_in[4];
    const float* Wa    = (const float*)d_in[5];
    const float* ba    = (const float*)d_in[6];
    const float* Wb    = (const float*)d_in[7];
    const float* bb    = (const float*)d_in[8];
    const float* Wo    = (const float*)d_in[9];
    const float* bo    = (const float*)d_in[10];
    float* out = (float*)d_out;

    char* ws = (char*)d_ws;
    u16*   leftT   = (u16*)ws;                      // 12288 x 256 bf16
    u16*   rightT  = (u16*)(ws + 6291456);
    float* normMat = (float*)(ws + 12582912);       // 384x384 f32
    u16*   WoB     = (u16*)(ws + 13172736);         // 128x1024 bf16

    k_prep<<<dim3(128), dim3(256), 0, stream>>>(Wo, WoB);
    k_lnproj<<<dim3(NRES, 4), dim3(256), 0, stream>>>(M, mask, gamma, beta,
                                                      Wa, ba, Wb, bb, leftT, rightT);
    k_norm<<<dim3(24, 24), dim3(256), 0, stream>>>(mask, normMat);
    k_main<<<dim3(96, 96), dim3(256), 0, stream>>>(leftT, rightT, normMat,
                                                   WoB, bo, Zraw, out);
}